// Round 12
// baseline (234.819 us; speedup 1.0000x reference)
//
#include <hip/hip_runtime.h>
#include <hip/hip_bf16.h>
#include <math.h>

// Problem constants
#define B_  8
#define N_  32
#define M_  16
#define LX  32
#define D_  64
#define IN_DIM_ 17
#define TT_ 63
#define H_  4
#define DH_ 16
#define P_TOT 4096          // B*N*M
#define BN_ 256             // B*N
#define FF_ 2048

// Fragment pool layout (slot = one short8/uint4 per lane-group entry)
#define FRAG_TOT 83200
#define OFF_INW  2048
#define OFF_OUTW 3584
#define OFF_FW1  4096
#define OFF_FW2  20480

typedef unsigned short ushort_t;
typedef __attribute__((ext_vector_type(8))) short short8;   // 8 bf16 (4 VGPRs)
typedef __attribute__((ext_vector_type(4))) float floatx4;  // MFMA C/D

#define MFMA16(a,b,c) __builtin_amdgcn_mfma_f32_16x16x32_bf16((a),(b),(c),0,0,0)

__device__ __forceinline__ float fast_exp2(float x){
#if __has_builtin(__builtin_amdgcn_exp2f)
  return __builtin_amdgcn_exp2f(x);
#else
  return __expf(x * 0.6931471805599453f);
#endif
}
__device__ __forceinline__ float fast_rcp(float x){
#if __has_builtin(__builtin_amdgcn_rcpf)
  return __builtin_amdgcn_rcpf(x);
#else
  return 1.0f / x;
#endif
}

__device__ __forceinline__ ushort_t f2bf(float f){          // RNE float->bf16
  unsigned u = __float_as_uint(f);
  u += 0x7FFFu + ((u >> 16) & 1u);
  return (ushort_t)(u >> 16);
}
__device__ __forceinline__ float bf2f(ushort_t h){ return __uint_as_float(((unsigned)h) << 16); }

__device__ __forceinline__ uint4 pack8(const ushort_t* h){
  uint4 u;
  u.x = (unsigned)h[0] | ((unsigned)h[1] << 16);
  u.y = (unsigned)h[2] | ((unsigned)h[3] << 16);
  u.z = (unsigned)h[4] | ((unsigned)h[5] << 16);
  u.w = (unsigned)h[6] | ((unsigned)h[7] << 16);
  return u;
}

// split 8 consecutive floats into hi/lo bf16 short8
__device__ __forceinline__ void split8(const float* r, short8& hi, short8& lo){
  #pragma unroll
  for (int j = 0; j < 8; ++j){
    float v = r[j];
    ushort_t h = f2bf(v);
    ushort_t l2 = f2bf(v - bf2f(h));
    hi[j] = (short)h; lo[j] = (short)l2;
  }
}
// hi-only conversion -> uint4
__device__ __forceinline__ uint4 cvt8(const float* r){
  ushort_t hh[8];
  #pragma unroll
  for (int j = 0; j < 8; ++j) hh[j] = f2bf(r[j]);
  return pack8(hh);
}
// hi-only conversion -> short8
__device__ __forceinline__ short8 cvt8s(const float* r){
  union { uint4 u4; short8 s8; } cv;
  cv.u4 = cvt8(r);
  return cv.s8;
}

// 3-term split product: (ah+al)(bh+bl) ~= ah*bh + ah*bl + al*bh
__device__ __forceinline__ floatx4 mm3(short8 ah, short8 al, short8 bh, short8 bl, floatx4 c){
  c = MFMA16(ah, bh, c); c = MFMA16(ah, bl, c); c = MFMA16(al, bh, c); return c;
}

__device__ __forceinline__ float dot64(const float* __restrict__ a, const float* __restrict__ w){
  const float4* a4 = (const float4*)a;
  const float4* w4 = (const float4*)w;
  float acc = 0.f;
  #pragma unroll
  for (int k = 0; k < 16; ++k){ float4 x = a4[k], y = w4[k];
    acc += x.x*y.x + x.y*y.y + x.z*y.z + x.w*y.w; }
  return acc;
}
__device__ __forceinline__ float dot16(const float* __restrict__ a, const float* __restrict__ b){
  const float4* a4 = (const float4*)a; const float4* b4 = (const float4*)b;
  float acc = 0.f;
  #pragma unroll
  for (int k = 0; k < 4; ++k){ float4 x = a4[k], y = b4[k];
    acc += x.x*y.x + x.y*y.y + x.z*y.z + x.w*y.w; }
  return acc;
}

// pack A-frags (16 tokens x 64 k) from stride-68 LDS buffer into fragA (hi[128], lo[128])
__device__ __forceinline__ void packA68(const float* buf, short8* fA, int tid){
  if (tid < 128){
    int ln = tid & 63, ks = tid >> 6;
    const float* r = buf + (ln & 15)*68 + ks*32 + ((ln >> 4) & 3)*8;
    short8 hi, lo; split8(r, hi, lo);
    fA[tid] = hi; fA[128 + tid] = lo;
  }
}

// -------------------------------------------------------------------------
// Prep: convert ALL weight matrices to MFMA B-fragment pool (hi at [s], lo at
// [FRAG_TOT+s]; lo only written for attn segments — ttcn + FF consume hi only).
// -------------------------------------------------------------------------
__global__ __launch_bounds__(256) void prep_kernel(
    const float* __restrict__ w1, const float* __restrict__ w2, const float* __restrict__ w3,
    const float* __restrict__ gqw, const float* __restrict__ gkw,
    const float* __restrict__ gvw, const float* __restrict__ gow,
    const float* __restrict__ inw, const float* __restrict__ outw,
    const float* __restrict__ fw1, const float* __restrict__ fw2,
    uint4* __restrict__ fr)
{
  int s = blockIdx.x*256 + threadIdx.x;
  if (s >= FRAG_TOT) return;
  const float* src; int Nr, Kr, KS, rel; int w3seg = 0, noLo = 0;
  if (s < 256)      { src = w1; Nr=63;  Kr=17; KS=1; rel = s; noLo = 1; }
  else if (s < 768) { src = w2; Nr=63;  Kr=63; KS=2; rel = s-256; noLo = 1; }
  else if (s < 9472){ src = w3; Nr=1071;Kr=63; KS=2; rel = s-768; w3seg = 1; noLo = 1; }
  else {
    int t = s - 9472, l = t / 36864, r2 = t - l*36864;
    if (r2 < 512)        { src = gqw + l*4096;   Nr=64;  Kr=64;   KS=2;  rel = r2; }
    else if (r2 < 1024)  { src = gkw + l*4096;   Nr=64;  Kr=64;   KS=2;  rel = r2-512; }
    else if (r2 < 1536)  { src = gvw + l*4096;   Nr=64;  Kr=64;   KS=2;  rel = r2-1024; }
    else if (r2 < 2048)  { src = gow + l*4096;   Nr=64;  Kr=64;   KS=2;  rel = r2-1536; }
    else if (r2 < 3584)  { src = inw + l*12288;  Nr=192; Kr=64;   KS=2;  rel = r2-2048; }
    else if (r2 < 4096)  { src = outw + l*4096;  Nr=64;  Kr=64;   KS=2;  rel = r2-3584; }
    else if (r2 < 20480) { src = fw1 + l*131072; Nr=2048;Kr=64;   KS=2;  rel = r2-4096; noLo = 1; }
    else                 { src = fw2 + l*131072; Nr=64;  Kr=2048; KS=64; rel = r2-20480; noLo = 1; }
  }
  int lane = rel & 63, tmp = rel >> 6;
  int ks = tmp % KS, nt = tmp / KS;
  int kb = ks*32 + ((lane >> 4) & 3)*8;
  int n, validn;
  if (w3seg){
    int i = nt >> 2, tq = nt & 3;
    int t = tq*16 + (lane & 15);
    n = t*17 + i;                         // source row of w3 (c = t*17+i)
    validn = (t < 63);
  } else {
    n = nt*16 + (lane & 15);
    validn = (n < Nr);
  }
  float v[8];
  #pragma unroll
  for (int j = 0; j < 8; ++j){
    v[j] = (validn && (kb + j) < Kr) ? src[n*Kr + kb + j] : 0.f;
    if (w3seg){
      if ((kb + j) == 63) v[j] = 1.0f;               // mask-carrier column
      v[j] *= 1.4426950408889634f;                   // log2(e) for exp2 epilogue
    }
  }
  ushort_t hh[8];
  #pragma unroll
  for (int j = 0; j < 8; ++j) hh[j] = f2bf(v[j]);
  fr[s] = pack8(hh);
  if (!noLo){
    ushort_t ll[8];
    #pragma unroll
    for (int j = 0; j < 8; ++j) ll[j] = f2bf(v[j] - bf2f(hh[j]));
    fr[FRAG_TOT + s] = pack8(ll);
  }
}

// -------------------------------------------------------------------------
// Fused TTCN (unchanged from R11) — bf16 1-term MFMA, fused P7.
// -------------------------------------------------------------------------
__global__ __launch_bounds__(256) void ttcn_kernel(
    const float* __restrict__ x, const int* __restrict__ mask,
    const float* __restrict__ b1, const float* __restrict__ b2,
    const float* __restrict__ tb,
    const short8* __restrict__ w1bhi,
    const short8* __restrict__ w2bhi,
    const short8* __restrict__ w3bhi,
    float* __restrict__ xp, float* __restrict__ pm)
{
  __shared__ __align__(16) char pool[16512];
  float*    xs    = (float*)(pool + 0);
  float*    xst   = (float*)(pool + 2560);
  float*    msv   = (float*)(pool + 5008);
  float*    xsumv = (float*)(pool + 5136);
  short8*   xfhi  = (short8*)(pool + 5216);
  ushort_t* h1t   = (ushort_t*)(pool + 7264);
  ushort_t* h2t   = (ushort_t*)(pool + 11872);

  const int p = blockIdx.x, tid = threadIdx.x;
  const int lane = tid & 63, wvi = tid >> 6;
  const int nidx = lane & 15, quad = lane >> 4;

  for (int idx = tid; idx < LX*IN_DIM_; idx += 256){
    int l = (idx * 3856) >> 16;
    int i = idx - l*17;
    xs[l*20 + i] = x[p*(LX*IN_DIM_) + idx];
  }
  if (tid < LX) msv[tid] = (float)mask[p*LX + tid];
  __syncthreads();

  if (tid < 128){
    int mt = tid >> 6;
    int l = mt*16 + nidx;
    float r[8];
    #pragma unroll
    for (int j = 0; j < 8; ++j){
      int k = quad*8 + j;
      r[j] = (k < IN_DIM_) ? xs[l*20 + k] : 0.f;
    }
    ((uint4*)xfhi)[tid] = cvt8(r);
  } else {
    if (tid < 128 + IN_DIM_){
      int i = tid - 128;
      float s = 0.f;
      #pragma unroll
      for (int l = 0; l < LX; ++l) s += xs[l*20 + i];
      xsumv[i] = s;
    }
    for (int idx = tid - 128; idx < 544; idx += 128){
      int i = idx >> 5, l = idx & 31;
      xst[i*36 + l] = xs[l*20 + i];
    }
  }
  __syncthreads();

  {
    short8 axh0 = xfhi[lane], axh1 = xfhi[64 + lane];
    short8 bh = w1bhi[wvi*64 + lane];
    floatx4 a0 = {0.f,0.f,0.f,0.f}, a1 = {0.f,0.f,0.f,0.f};
    a0 = MFMA16(axh0, bh, a0);
    a1 = MFMA16(axh1, bh, a1);
    int t = wvi*16 + nidx;
    float bb = (t < TT_) ? b1[t] : 0.f;
    #pragma unroll
    for (int r = 0; r < 4; ++r){
      h1t[(quad*4+r)*72 + t]      = f2bf(fmaxf(a0[r] + bb, 0.f));
      h1t[(16+quad*4+r)*72 + t]   = f2bf(fmaxf(a1[r] + bb, 0.f));
    }
  }
  __syncthreads();

  {
    short8 ah[2][2];
    #pragma unroll
    for (int mt = 0; mt < 2; ++mt)
      #pragma unroll
      for (int ks = 0; ks < 2; ++ks){
        int l = mt*16 + nidx;
        ah[mt][ks] = *(const short8*)((const char*)h1t + (l*72 + ks*32 + quad*8)*2);
      }
    short8 bh0 = w2bhi[(wvi*2+0)*64 + lane];
    short8 bh1 = w2bhi[(wvi*2+1)*64 + lane];
    floatx4 a0 = {0.f,0.f,0.f,0.f}, a1 = {0.f,0.f,0.f,0.f};
    a0 = MFMA16(ah[0][0], bh0, a0); a0 = MFMA16(ah[0][1], bh1, a0);
    a1 = MFMA16(ah[1][0], bh0, a1); a1 = MFMA16(ah[1][1], bh1, a1);
    int t = wvi*16 + nidx;
    float bb = (t < TT_) ? b2[t] : 0.f;
    #pragma unroll
    for (int r = 0; r < 4; ++r){
      h2t[(quad*4+r)*72 + t]      = f2bf(fmaxf(a0[r] + bb, 0.f));
      h2t[(16+quad*4+r)*72 + t]   = f2bf(fmaxf(a1[r] + bb, 0.f));
    }
  }
  __syncthreads();

  {
    short8 ah[2][2];
    #pragma unroll
    for (int mt = 0; mt < 2; ++mt)
      #pragma unroll
      for (int ks = 0; ks < 2; ++ks){
        int l = mt*16 + nidx;
        ah[mt][ks] = *(const short8*)((const char*)h2t + (l*72 + ks*32 + quad*8)*2);
      }
    if (quad == 3){
      ah[0][1][7] = (short)((msv[nidx]      == 0.f) ? f2bf(-1e8f) : (ushort_t)0);
      ah[1][1][7] = (short)((msv[16 + nidx] == 0.f) ? f2bf(-1e8f) : (ushort_t)0);
    }
    const int t_out = wvi*16 + nidx;
    const int rA = quad*4;
    float acc_t = 0.f;
    short8 nbh0 = w3bhi[(wvi*2+0)*64 + lane];
    short8 nbh1 = w3bhi[(wvi*2+1)*64 + lane];
    for (int it = 0; it < 17; ++it){
      short8 bh0 = nbh0, bh1 = nbh1;
      if (it < 16){
        int nt = wvi + it*4 + 4;
        nbh0 = w3bhi[(nt*2+0)*64 + lane];
        nbh1 = w3bhi[(nt*2+1)*64 + lane];
      }
      floatx4 a0 = {0.f,0.f,0.f,0.f}, a1 = {0.f,0.f,0.f,0.f};
      a0 = MFMA16(ah[0][0], bh0, a0); a0 = MFMA16(ah[0][1], bh1, a0);
      a1 = MFMA16(ah[1][0], bh0, a1); a1 = MFMA16(ah[1][1], bh1, a1);

      const float4 xA = *(const float4*)(xst + it*36 + rA);
      const float4 xB = *(const float4*)(xst + it*36 + rA + 16);
      float den0 = 0.f, den1 = 0.f, num0 = 0.f, num1 = 0.f;
      float e;
      e = fast_exp2(a0[0]); den0 += e; num0 = fmaf(e, xA.x, num0);
      e = fast_exp2(a0[1]); den0 += e; num0 = fmaf(e, xA.y, num0);
      e = fast_exp2(a0[2]); den0 += e; num0 = fmaf(e, xA.z, num0);
      e = fast_exp2(a0[3]); den0 += e; num0 = fmaf(e, xA.w, num0);
      e = fast_exp2(a1[0]); den1 += e; num1 = fmaf(e, xB.x, num1);
      e = fast_exp2(a1[1]); den1 += e; num1 = fmaf(e, xB.y, num1);
      e = fast_exp2(a1[2]); den1 += e; num1 = fmaf(e, xB.z, num1);
      e = fast_exp2(a1[3]); den1 += e; num1 = fmaf(e, xB.w, num1);
      float den = den0 + den1, num = num0 + num1;
      den += __shfl_xor(den, 16, 64); den += __shfl_xor(den, 32, 64);
      num += __shfl_xor(num, 16, 64); num += __shfl_xor(num, 32, 64);
      float res = (den > 0.f) ? num * fast_rcp(den) : xsumv[it] * (1.f/32.f);
      acc_t += res;
    }
    if (quad == 0 && t_out < TT_)
      xp[p*D_ + t_out] = fmaxf(acc_t + tb[t_out], 0.f);
  }
  if (tid == 63){
    float s = 0.f;
    #pragma unroll
    for (int l = 0; l < LX; ++l) s += msv[l];
    float mp = (s > 0.f) ? 1.f : 0.f;
    xp[p*D_ + TT_] = mp;
    pm[p] = mp;
  }
}

// -------------------------------------------------------------------------
// BOTH transformer layers fused — 512 threads (8 waves = 2 waves/SIMD for
// real TLP latency hiding). FF serial chain halved (8 iters/wave). LDS held
// under 64 KB: pe table recomputed, ss/ao unioned with hbuf/part, FF partials
// combined in two passes over a 4-slot buffer.
// Task maps: QKV = 12 tile-tasks (waves 0-7 take task w8; waves 0-3 also
// task 8+w8 = v-tiles). gattn-out on waves 0-3, MHA-out on waves 4-7.
// -------------------------------------------------------------------------
__global__ __launch_bounds__(512) void layer12_kernel(
    const float* __restrict__ xin, const float* __restrict__ pm,
    const short8* __restrict__ frS,
    const float* __restrict__ gqb, const float* __restrict__ gkb,
    const float* __restrict__ gvb, const float* __restrict__ gob,
    const float* __restrict__ inb, const float* __restrict__ outb,
    const float* __restrict__ ln1g, const float* __restrict__ ln1b,
    const float* __restrict__ fb1, const float* __restrict__ fb2,
    const float* __restrict__ ln2g, const float* __restrict__ ln2b,
    float* __restrict__ xout)
{
  __shared__ __align__(16) float xb[16*68];
  __shared__ __align__(16) float xb2[16*68];
  __shared__ __align__(16) float q_[16*68];
  __shared__ __align__(16) float k_[16*68];
  __shared__ __align__(16) float v_[16*68];
  __shared__ __align__(16) short8 fragA[256];
  __shared__ __align__(16) float scratch[8960];  // ss[1024]+ao[1088] | hbuf[4608]+part[4352]
  __shared__ float tbt[16];
  __shared__ float pmv[16], mur[16], rvr[16];

  float* ss   = scratch;
  float* ao   = scratch + 1024;
  float* hbuf = scratch;             // FF-phase alias (ss/ao dead there)
  float* part = scratch + 4608;

  const int bn = blockIdx.x, tid = threadIdx.x;
  const int lane = tid & 63, w8 = tid >> 6;      // 8 waves
  const int nidx = lane & 15, quad = lane >> 4;
  const float* xin_p = xin + bn*1024;

  for (int o = tid; o < 1024; o += 512) xb[(o>>6)*68 + (o&63)] = xin_p[o];
  if (tid < 16) pmv[tid] = pm[bn*16 + tid];
  if (tid >= 32 && tid < 48) tbt[tid-32] = logf(expf(-5.0f*(float)(tid-32)) + 1e-12f);
  __syncthreads();

  for (int l = 0; l < 2; ++l){
    const int lbase = 9472 + l*36864;
    const float* gqbL = gqb + l*64;  const float* gkbL = gkb + l*64;
    const float* gvbL = gvb + l*64;  const float* gobL = gob + l*64;
    const float* inbL = inb + l*192; const float* outbL = outb + l*64;
    const float* ln1gL = ln1g + l*64; const float* ln1bL = ln1b + l*64;
    const float* fb1L = fb1 + l*2048; const float* fb2L = fb2 + l*64;
    const float* ln2gL = ln2g + l*64; const float* ln2bL = ln2b + l*64;

    // save layer input (for l==1 residual): 2 elems/thread
    float xres[2];
    #pragma unroll
    for (int j = 0; j < 2; ++j){
      int o = tid + j*512;
      xres[j] = xb[(o>>6)*68 + (o&63)];
    }

    // ===== PREFETCH 1: gattn QKV (tasks w8, 8+w8), gattn-out (w0-3), MHA QKV
    short8 gbA[4], gbB[4], obf[4], mbA[4], mbB[4];
    {
      int t = w8, mat = t >> 2, nt = t & 3;
      int base = lbase + mat*512 + (nt*2)*64;
      gbA[0] = frS[base + lane];        gbA[1] = frS[FRAG_TOT + base + lane];
      gbA[2] = frS[base + 64 + lane];   gbA[3] = frS[FRAG_TOT + base + 64 + lane];
      int baseM = lbase + OFF_INW + t*128;
      mbA[0] = frS[baseM + lane];       mbA[1] = frS[FRAG_TOT + baseM + lane];
      mbA[2] = frS[baseM + 64 + lane];  mbA[3] = frS[FRAG_TOT + baseM + 64 + lane];
    }
    if (w8 < 4){
      int t = 8 + w8, nt = t & 3;               // mat == 2 (v)
      int base = lbase + 2*512 + (nt*2)*64;
      gbB[0] = frS[base + lane];        gbB[1] = frS[FRAG_TOT + base + lane];
      gbB[2] = frS[base + 64 + lane];   gbB[3] = frS[FRAG_TOT + base + 64 + lane];
      int baseM = lbase + OFF_INW + t*128;
      mbB[0] = frS[baseM + lane];       mbB[1] = frS[FRAG_TOT + baseM + lane];
      mbB[2] = frS[baseM + 64 + lane];  mbB[3] = frS[FRAG_TOT + baseM + 64 + lane];
      int baseO = lbase + 1536 + (w8*2)*64;     // gattn out, nt = w8
      obf[0] = frS[baseO + lane];       obf[1] = frS[FRAG_TOT + baseO + lane];
      obf[2] = frS[baseO + 64 + lane];  obf[3] = frS[FRAG_TOT + baseO + 64 + lane];
    }

    // ---- gattn QKV ----
    packA68(xb, fragA, tid);
    __syncthreads();
    {
      short8 axh0 = fragA[lane], axh1 = fragA[64+lane];
      short8 axl0 = fragA[128+lane], axl1 = fragA[192+lane];
      {
        int t = w8, mat = t >> 2, nt = t & 3;
        floatx4 c = {0.f,0.f,0.f,0.f};
        c = mm3(axh0, axl0, gbA[0], gbA[1], c);
        c = mm3(axh1, axl1, gbA[2], gbA[3], c);
        int d = nt*16 + nidx;
        float bb = (mat == 0 ? gqbL : mat == 1 ? gkbL : gvbL)[d];
        float* dst = (mat == 0 ? q_ : mat == 1 ? k_ : v_);
        #pragma unroll
        for (int r = 0; r < 4; ++r) dst[(quad*4+r)*68 + d] = c[r] + bb;
      }
      if (w8 < 4){
        int nt = w8;                            // task 8+w8, mat 2 -> v
        floatx4 c = {0.f,0.f,0.f,0.f};
        c = mm3(axh0, axl0, gbB[0], gbB[1], c);
        c = mm3(axh1, axl1, gbB[2], gbB[3], c);
        int d = nt*16 + nidx;
        float bb = gvbL[d];
        #pragma unroll
        for (int r = 0; r < 4; ++r) v_[(quad*4+r)*68 + d] = c[r] + bb;
      }
    }
    __syncthreads();
    // ---- merged scores+softmax (256 threads, 4-lane groups) ----
    if (tid < 256){
      int row = tid >> 2;
      int h = row >> 4, qm = row & 15;
      int km0 = (tid & 3) * 4;
      float s4[4];
      #pragma unroll
      for (int j = 0; j < 4; ++j){
        int km = km0 + j;
        float acc = dot16(q_ + qm*68 + h*16, k_ + km*68 + h*16);
        int dd = qm - km; if (dd < 0) dd = -dd;
        acc = acc * 0.25f + tbt[dd];
        if (pmv[km] == 0.f) acc = -1e9f;
        s4[j] = acc;
      }
      float mx = fmaxf(fmaxf(s4[0], s4[1]), fmaxf(s4[2], s4[3]));
      mx = fmaxf(mx, __shfl_xor(mx, 1, 64));
      mx = fmaxf(mx, __shfl_xor(mx, 2, 64));
      float e4[4], se = 0.f;
      #pragma unroll
      for (int j = 0; j < 4; ++j){ e4[j] = __expf(s4[j]-mx); se += e4[j]; }
      se += __shfl_xor(se, 1, 64);
      se += __shfl_xor(se, 2, 64);
      float inv = fast_rcp(se);
      #pragma unroll
      for (int j = 0; j < 4; ++j) ss[row*16 + km0 + j] = e4[j]*inv;
    }
    __syncthreads();
    for (int o = tid; o < 1024; o += 512){
      int m = o >> 6, d = o & 63, h = d >> 4;
      float acc = 0.f;
      #pragma unroll
      for (int km = 0; km < 16; ++km) acc += ss[h*256 + m*16 + km] * v_[km*68 + d];
      ao[m*68 + d] = acc;
    }
    __syncthreads();
    packA68(ao, fragA, tid);
    __syncthreads();
    if (w8 < 4){
      short8 axh0 = fragA[lane], axh1 = fragA[64+lane];
      short8 axl0 = fragA[128+lane], axl1 = fragA[192+lane];
      floatx4 c = {0.f,0.f,0.f,0.f};
      c = mm3(axh0, axl0, obf[0], obf[1], c);
      c = mm3(axh1, axl1, obf[2], obf[3], c);
      int d = w8*16 + nidx;
      float bb = gobL[d];
      float div = __expf((float)(d & ~1) * (-0.14391156831212793f)); // -ln(1e4)/64
      #pragma unroll
      for (int r = 0; r < 4; ++r){
        int tok = quad*4 + r;
        float arg = (float)tok * div;
        float pev = (d & 1) ? cosf(arg) : sinf(arg);
        xb[tok*68 + d] += (c[r] + bb) * pmv[tok] + pev;
      }
    }
    __syncthreads();

    // ===== PREFETCH 2: MHA-out (waves 4-7) + FF initial f1/f2 (all waves)
    short8 mob[4], f1c[4], f2c[4];
    if (w8 >= 4){
      int base = lbase + OFF_OUTW + (w8-4)*128;
      mob[0] = frS[base + lane];       mob[1] = frS[FRAG_TOT + base + lane];
      mob[2] = frS[base + 64 + lane];  mob[3] = frS[FRAG_TOT + base + 64 + lane];
    }
    {
      int f1base = lbase + OFF_FW1, f2base = lbase + OFF_FW2;
      #pragma unroll
      for (int t2 = 0; t2 < 2; ++t2){
        int sb = f1base + ((w8*16+t2)*2)*64 + lane;
        f1c[t2*2+0] = frS[sb];
        f1c[t2*2+1] = frS[sb + 64];
      }
      #pragma unroll
      for (int ntd = 0; ntd < 4; ++ntd)
        f2c[ntd] = frS[f2base + (ntd*64 + w8*8)*64 + lane];
    }

    // ---- MHA QKV ----
    packA68(xb, fragA, tid);
    __syncthreads();
    {
      short8 axh0 = fragA[lane], axh1 = fragA[64+lane];
      short8 axl0 = fragA[128+lane], axl1 = fragA[192+lane];
      {
        int t = w8, mat = t >> 2, nt = t & 3;
        floatx4 c = {0.f,0.f,0.f,0.f};
        c = mm3(axh0, axl0, mbA[0], mbA[1], c);
        c = mm3(axh1, axl1, mbA[2], mbA[3], c);
        int d = nt*16 + nidx;
        float bb = inbL[t*16 + nidx];
        float* dst = (mat == 0 ? q_ : mat == 1 ? k_ : v_);
        #pragma unroll
        for (int r = 0; r < 4; ++r) dst[(quad*4+r)*68 + d] = c[r] + bb;
      }
      if (w8 < 4){
        int t = 8 + w8, nt = t & 3;             // mat 2 -> v
        floatx4 c = {0.f,0.f,0.f,0.f};
        c = mm3(axh0, axl0, mbB[0], mbB[1], c);
        c = mm3(axh1, axl1, mbB[2], mbB[3], c);
        int d = nt*16 + nidx;
        float bb = inbL[t*16 + nidx];
        #pragma unroll
        for (int r = 0; r < 4; ++r) v_[(quad*4+r)*68 + d] = c[r] + bb;
      }
    }
    __syncthreads();
    if (tid < 256){
      int row = tid >> 2;
      int h = row >> 4, qm = row & 15;
      int km0 = (tid & 3) * 4;
      float s4[4];
      #pragma unroll
      for (int j = 0; j < 4; ++j)
        s4[j] = 0.25f * dot16(q_ + qm*68 + h*16, k_ + (km0+j)*68 + h*16);
      float mx = fmaxf(fmaxf(s4[0], s4[1]), fmaxf(s4[2], s4[3]));
      mx = fmaxf(mx, __shfl_xor(mx, 1, 64));
      mx = fmaxf(mx, __shfl_xor(mx, 2, 64));
      float e4[4], se = 0.f;
      #pragma unroll
      for (int j = 0; j < 4; ++j){ e4[j] = __expf(s4[j]-mx); se += e4[j]; }
      se += __shfl_xor(se, 1, 64);
      se += __shfl_xor(se, 2, 64);
      float inv = fast_rcp(se);
      #pragma unroll
      for (int j = 0; j < 4; ++j) ss[row*16 + km0 + j] = e4[j]*inv;
    }
    __syncthreads();
    for (int o = tid; o < 1024; o += 512){
      int m = o >> 6, d = o & 63, h = d >> 4;
      float acc = 0.f;
      #pragma unroll
      for (int km = 0; km < 16; ++km) acc += ss[h*256 + m*16 + km] * v_[km*68 + d];
      ao[m*68 + d] = acc;
    }
    __syncthreads();
    packA68(ao, fragA, tid);
    __syncthreads();
    if (w8 >= 4){
      short8 axh0 = fragA[lane], axh1 = fragA[64+lane];
      short8 axl0 = fragA[128+lane], axl1 = fragA[192+lane];
      floatx4 c = {0.f,0.f,0.f,0.f};
      c = mm3(axh0, axl0, mob[0], mob[1], c);
      c = mm3(axh1, axl1, mob[2], mob[3], c);
      int d = (w8-4)*16 + nidx;
      float bb = outbL[d];
      #pragma unroll
      for (int r = 0; r < 4; ++r) xb[(quad*4+r)*68 + d] += c[r] + bb;
    }
    __syncthreads();

    // ---- LN1 (64 threads, 4 lanes/row) -> xb2 ----
    if (tid < 64){
      int row = tid >> 2, seg = tid & 3;
      const float* rp = xb + row*68 + seg*16;
      float s = 0.f;
      #pragma unroll
      for (int j = 0; j < 16; ++j) s += rp[j];
      s += __shfl_xor(s, 1, 64); s += __shfl_xor(s, 2, 64);
      float mu = s * (1.f/64.f);
      float v = 0.f;
      #pragma unroll
      for (int j = 0; j < 16; ++j){ float t = rp[j]-mu; v += t*t; }
      v += __shfl_xor(v, 1, 64); v += __shfl_xor(v, 2, 64);
      if (seg == 0){ mur[row] = mu; rvr[row] = rsqrtf(v*(1.f/64.f) + 1e-5f); }
    }
    __syncthreads();
    for (int o = tid; o < 1024; o += 512){
      int m = o >> 6, d = o & 63;
      xb2[m*68 + d] = (xb[m*68 + d] - mur[m]) * rvr[m] * ln1gL[d] + ln1bL[d];
    }
    __syncthreads();
    packA68(xb2, fragA, tid);
    __syncthreads();

    // ---- FF: 8 waves x 256 hidden, 8 ksteps each; f1/f2 prefetch 1 ahead
    floatx4 y0 = {0.f,0.f,0.f,0.f}, y1 = y0, y2 = y0, y3 = y0;
    {
      const int f1base = lbase + OFF_FW1, f2base = lbase + OFF_FW2;
      short8 axh0 = fragA[lane], axh1 = fragA[64 + lane];
      float* hw = hbuf + w8*576;

      short8 f1n[4], f2n[4];
      for (int it = 0; it < 8; ++it){
        int ntA = w8*16 + it*2;
        floatx4 hA = {0.f,0.f,0.f,0.f}, hB = hA;
        hA = MFMA16(axh0, f1c[0], hA); hA = MFMA16(axh1, f1c[1], hA);
        hB = MFMA16(axh0, f1c[2], hB); hB = MFMA16(axh1, f1c[3], hB);
        float bbA = fb1L[ntA*16 + nidx], bbB = fb1L[ntA*16 + 16 + nidx];
        #pragma unroll
        for (int r = 0; r < 4; ++r){
          hw[(quad*4+r)*36 + nidx]      = fmaxf(hA[r] + bbA, 0.f);
          hw[(quad*4+r)*36 + 16 + nidx] = fmaxf(hB[r] + bbB, 0.f);
        }
        if (it < 7){
          int ntN = ntA + 2, kstN = w8*8 + it + 1;
          #pragma unroll
          for (int t2 = 0; t2 < 2; ++t2){
            int sb = f1base + ((ntN+t2)*2)*64 + lane;
            f1n[t2*2+0] = frS[sb];
            f1n[t2*2+1] = frS[sb + 64];
          }
          #pragma unroll
          for (int ntd = 0; ntd < 4; ++ntd)
            f2n[ntd] = frS[f2base + (ntd*64 + kstN)*64 + lane];
        }
        short8 ah = cvt8s(hw + (lane & 15)*36 + quad*8);
        y0 = MFMA16(ah, f2c[0], y0);
        y1 = MFMA16(ah, f2c[1], y1);
        y2 = MFMA16(ah, f2c[2], y2);
        y3 = MFMA16(ah, f2c[3], y3);
        #pragma unroll
        for (int j = 0; j < 4; ++j){ f1c[j] = f1n[j]; f2c[j] = f2n[j]; }
      }
    }
    // two-pass partial combine (4-slot buffer)
    if (w8 < 4){
      #pragma unroll
      for (int r = 0; r < 4; ++r){
        int row = (quad*4 + r)*68;
        part[w8*1088 + row + nidx]      = y0[r];
        part[w8*1088 + row + 16 + nidx] = y1[r];
        part[w8*1088 + row + 32 + nidx] = y2[r];
        part[w8*1088 + row + 48 + nidx] = y3[r];
      }
    }
    __syncthreads();
    float xacc[2];
    #pragma unroll
    for (int j = 0; j < 2; ++j){
      int o = tid + j*512, tok = o >> 6, d = o & 63;
      float s = xb2[tok*68 + d] + fb2L[d];
      #pragma unroll
      for (int ww = 0; ww < 4; ++ww) s += part[ww*1088 + tok*68 + d];
      xacc[j] = s;
    }
    __syncthreads();
    if (w8 >= 4){
      #pragma unroll
      for (int r = 0; r < 4; ++r){
        int row = (quad*4 + r)*68;
        part[(w8-4)*1088 + row + nidx]      = y0[r];
        part[(w8-4)*1088 + row + 16 + nidx] = y1[r];
        part[(w8-4)*1088 + row + 32 + nidx] = y2[r];
        part[(w8-4)*1088 + row + 48 + nidx] = y3[r];
      }
    }
    __syncthreads();
    #pragma unroll
    for (int j = 0; j < 2; ++j){
      int o = tid + j*512, tok = o >> 6, d = o & 63;
      #pragma unroll
      for (int ww = 0; ww < 4; ++ww) xacc[j] += part[ww*1088 + tok*68 + d];
      xb[tok*68 + d] = xacc[j];
    }
    __syncthreads();
    // ---- LN2 (64 threads) + layer-1 residual ----
    if (tid < 64){
      int row = tid >> 2, seg = tid & 3;
      const float* rp = xb + row*68 + seg*16;
      float s = 0.f;
      #pragma unroll
      for (int j = 0; j < 16; ++j) s += rp[j];
      s += __shfl_xor(s, 1, 64); s += __shfl_xor(s, 2, 64);
      float mu = s * (1.f/64.f);
      float v = 0.f;
      #pragma unroll
      for (int j = 0; j < 16; ++j){ float t = rp[j]-mu; v += t*t; }
      v += __shfl_xor(v, 1, 64); v += __shfl_xor(v, 2, 64);
      if (seg == 0){ mur[row] = mu; rvr[row] = rsqrtf(v*(1.f/64.f) + 1e-5f); }
    }
    __syncthreads();
    #pragma unroll
    for (int j = 0; j < 2; ++j){
      int o = tid + j*512, tok = o >> 6, d = o & 63;
      float vv = (xb[tok*68 + d] - mur[tok]) * rvr[tok] * ln2gL[d] + ln2bL[d];
      if (l == 0) xb[tok*68 + d] = vv;
      else        xout[bn*1024 + o] = vv + xres[j];
    }
    __syncthreads();
  }
}

// -------------------------------------------------------------------------
// Classifier head. One block per b. (small; fp32)
// -------------------------------------------------------------------------
__global__ __launch_bounds__(256) void final_kernel(
    const float* __restrict__ xc, const float* __restrict__ pm,
    const float* __restrict__ q_embed,
    const float* __restrict__ cin_w, const float* __restrict__ cin_b,
    const float* __restrict__ cout_w, const float* __restrict__ cout_b,
    const float* __restrict__ logit_w, const float* __restrict__ logit_b,
    float* __restrict__ out)
{
  const int b = blockIdx.x;
  const int tid = threadIdx.x;
  __shared__ __align__(16) float xs[M_ * D_];
  __shared__ float kpmv[M_];
  __shared__ __align__(16) float qv[5 * D_], kv[M_ * D_], vv[M_ * D_];
  __shared__ float sv[H_ * 5 * M_];
  __shared__ __align__(16) float ao[5 * D_], zv[5 * D_];

  for (int o = tid; o < M_ * D_; o += 256) {
    int m = o >> 6, d = o & 63;
    float acc = 0.f;
    #pragma unroll
    for (int n = 0; n < N_; ++n) acc += xc[(((b * N_ + n) * M_ + m) * D_) + d];
    xs[o] = acc * (1.f / 32.f);
  }
  if (tid < M_) {
    float any = 0.f;
    #pragma unroll
    for (int n = 0; n < N_; ++n) any += (pm[(b * N_ + n) * M_ + tid] > 0.f) ? 1.f : 0.f;
    kpmv[tid] = (any > 0.f) ? 0.f : 1.f;
  }
  __syncthreads();

  for (int o = tid; o < 5 * D_; o += 256) {
    int qi = o >> 6, d = o & 63;
    qv[o] = cin_b[d] + dot64(q_embed + qi * D_, cin_w + d * D_);
  }
  for (int o = tid; o < 2 * M_ * D_; o += 256) {
    int sel = o >> 10, r = o & 1023, m = r >> 6, d = r & 63;
    float acc = cin_b[D_ + sel * D_ + d] + dot64(xs + m * D_, cin_w + (D_ + sel * D_ + d) * D_);
    ((sel == 0) ? kv : vv)[r] = acc;
  }
  __syncthreads();

  for (int o = tid; o < H_ * 5 * M_; o += 256) {
    int h = o / 80, r = o % 80, qi = r >> 4, km = r & 15;
    float acc = 0.25f * dot16(qv + qi * D_ + h * DH_, kv + km * D_ + h * DH_);
    if (kpmv[km] != 0.f) acc = -1e9f;
    sv[o] = acc;
  }
  __syncthreads();
  if (tid < H_ * 5) {
    int h = tid / 5, qi = tid % 5;
    float* row = sv + h * 80 + qi * M_;
    float mx = -1e30f;
    #pragma unroll
    for (int km = 0; km < M_; ++km) mx = fmaxf(mx, row[km]);
    float se = 0.f;
    #pragma unroll
    for (int km = 0; km < M_; ++km) { float e = __expf(row[km] - mx); row[km] = e; se += e; }
    float inv = 1.f / se;
    #pragma unroll
    for (int km = 0; km < M_; ++km) row[km] *= inv;
  }
  __syncthreads();
  for (int o = tid; o < 5 * D_; o += 256) {
    int qi = o >> 6, d = o & 63, h = d >> 4;
    float acc = 0.f;
    #pragma unroll
    for (int km = 0; km < M_; ++km) acc += sv[h * 80 + qi * M_ + km] * vv[km * D_ + d];
    ao[o] = acc;
  }
  __syncthreads();
  for (int o = tid; o < 5 * D_; o += 256) {
    int qi = o >> 6, d = o & 63;
    zv[o] = cout_b[d] + dot64(ao + qi * D_, cout_w + d * D_);
  }
  __syncthreads();
  if (tid < 5) {
    float acc = logit_b[0] + dot64(zv + tid * D_, logit_w);
    out[b * 5 + tid] = acc;
  }
}

// -------------------------------------------------------------------------
extern "C" void kernel_launch(void* const* d_in, const int* in_sizes, int n_in,
                              void* d_out, int out_size, void* d_ws, size_t ws_size,
                              hipStream_t stream) {
  const float* x       = (const float*)d_in[0];
  const int*   mask    = (const int*)  d_in[1];
  const float* ttcn_w1 = (const float*)d_in[2];
  const float* ttcn_b1 = (const float*)d_in[3];
  const float* ttcn_w2 = (const float*)d_in[4];
  const float* ttcn_b2 = (const float*)d_in[5];
  const float* ttcn_w3 = (const float*)d_in[6];
  const float* ttcn_b3 = (const float*)d_in[7];   // unused: cancels in softmax
  const float* t_bias  = (const float*)d_in[8];
  const float* ga_qw   = (const float*)d_in[9];
  const float* ga_qb   = (const float*)d_in[10];
  const float* ga_kw   = (const float*)d_in[11];
  const float* ga_kb   = (const float*)d_in[12];
  const float* ga_vw   = (const float*)d_in[13];
  const float* ga_vb   = (const float*)d_in[14];
  const float* ga_ow   = (const float*)d_in[15];
  const float* ga_ob   = (const float*)d_in[16];
  const float* tf_in_w = (const float*)d_in[17];
  const float* tf_in_b = (const float*)d_in[18];
  const float* tf_out_w= (const float*)d_in[19];
  const float* tf_out_b= (const float*)d_in[20];
  const float* tf_ln1g = (const float*)d_in[21];
  const float* tf_ln1b = (const float*)d_in[22];
  const float* tf_ln2g = (const float*)d_in[23];
  const float* tf_ln2b = (const float*)d_in[24];
  const float* tf_fw1  = (const float*)d_in[25];
  const float* tf_fb1  = (const float*)d_in[26];
  const float* tf_fw2  = (const float*)d_in[27];
  const float* tf_fb2  = (const float*)d_in[28];
  const float* q_embed = (const float*)d_in[29];
  const float* cls_in_w  = (const float*)d_in[30];
  const float* cls_in_b  = (const float*)d_in[31];
  const float* cls_out_w = (const float*)d_in[32];
  const float* cls_out_b = (const float*)d_in[33];
  const float* logit_w = (const float*)d_in[34];
  const float* logit_b = (const float*)d_in[35];
  (void)ttcn_b3;

  float* wsf  = (float*)d_ws;
  float* xp   = wsf;                        // 262144 f
  float* pmb  = wsf + P_TOT * D_;           // 4096 f
  float* xbuf = pmb + P_TOT;                // 262144 f
  uint4* fr   = (uint4*)(xbuf + P_TOT * D_);// 2*FRAG_TOT uint4
  const short8* frS = (const short8*)fr;

  prep_kernel<<<325, 256, 0, stream>>>(ttcn_w1, ttcn_w2, ttcn_w3,
      ga_qw, ga_kw, ga_vw, ga_ow, tf_in_w, tf_out_w, tf_fw1, tf_fw2, fr);

  ttcn_kernel<<<P_TOT, 256, 0, stream>>>(x, mask, ttcn_b1, ttcn_b2, t_bias,
      frS + 0, frS + 256, frS + 768,
      xp, pmb);

  layer12_kernel<<<BN_, 512, 0, stream>>>(xp, pmb, frS,
      ga_qb, ga_kb, ga_vb, ga_ob, tf_in_b, tf_out_b, tf_ln1g, tf_ln1b,
      tf_fb1, tf_fb2, tf_ln2g, tf_ln2b, xbuf);

  final_kernel<<<B_, 256, 0, stream>>>(xbuf, pmb, q_embed,
                                       cls_in_w, cls_in_b, cls_out_w, cls_out_b,
                                       logit_w, logit_b, (float*)d_out);
}

// Round 13
// 232.320 us; speedup vs baseline: 1.0108x; 1.0108x over previous
//
#include <hip/hip_runtime.h>
#include <hip/hip_bf16.h>
#include <math.h>

// Problem constants
#define B_  8
#define N_  32
#define M_  16
#define LX  32
#define D_  64
#define IN_DIM_ 17
#define TT_ 63
#define H_  4
#define DH_ 16
#define P_TOT 4096          // B*N*M
#define BN_ 256             // B*N
#define FF_ 2048

// Fragment pool layout (slot = one short8/uint4 per lane-group entry)
#define FRAG_TOT 83200
#define OFF_INW  2048
#define OFF_OUTW 3584
#define OFF_FW1  4096
#define OFF_FW2  20480

typedef unsigned short ushort_t;
typedef __attribute__((ext_vector_type(8))) short short8;   // 8 bf16 (4 VGPRs)
typedef __attribute__((ext_vector_type(4))) float floatx4;  // MFMA C/D

#define MFMA16(a,b,c) __builtin_amdgcn_mfma_f32_16x16x32_bf16((a),(b),(c),0,0,0)

__device__ __forceinline__ float fast_exp2(float x){
#if __has_builtin(__builtin_amdgcn_exp2f)
  return __builtin_amdgcn_exp2f(x);
#else
  return __expf(x * 0.6931471805599453f);
#endif
}
__device__ __forceinline__ float fast_rcp(float x){
#if __has_builtin(__builtin_amdgcn_rcpf)
  return __builtin_amdgcn_rcpf(x);
#else
  return 1.0f / x;
#endif
}

__device__ __forceinline__ ushort_t f2bf(float f){          // RNE float->bf16
  unsigned u = __float_as_uint(f);
  u += 0x7FFFu + ((u >> 16) & 1u);
  return (ushort_t)(u >> 16);
}
__device__ __forceinline__ float bf2f(ushort_t h){ return __uint_as_float(((unsigned)h) << 16); }

__device__ __forceinline__ uint4 pack8(const ushort_t* h){
  uint4 u;
  u.x = (unsigned)h[0] | ((unsigned)h[1] << 16);
  u.y = (unsigned)h[2] | ((unsigned)h[3] << 16);
  u.z = (unsigned)h[4] | ((unsigned)h[5] << 16);
  u.w = (unsigned)h[6] | ((unsigned)h[7] << 16);
  return u;
}

// split 8 consecutive floats into hi/lo bf16 short8
__device__ __forceinline__ void split8(const float* r, short8& hi, short8& lo){
  #pragma unroll
  for (int j = 0; j < 8; ++j){
    float v = r[j];
    ushort_t h = f2bf(v);
    ushort_t l2 = f2bf(v - bf2f(h));
    hi[j] = (short)h; lo[j] = (short)l2;
  }
}
// hi-only conversion -> uint4
__device__ __forceinline__ uint4 cvt8(const float* r){
  ushort_t hh[8];
  #pragma unroll
  for (int j = 0; j < 8; ++j) hh[j] = f2bf(r[j]);
  return pack8(hh);
}
// hi-only conversion -> short8
__device__ __forceinline__ short8 cvt8s(const float* r){
  union { uint4 u4; short8 s8; } cv;
  cv.u4 = cvt8(r);
  return cv.s8;
}

// 3-term split product: (ah+al)(bh+bl) ~= ah*bh + ah*bl + al*bh
__device__ __forceinline__ floatx4 mm3(short8 ah, short8 al, short8 bh, short8 bl, floatx4 c){
  c = MFMA16(ah, bh, c); c = MFMA16(ah, bl, c); c = MFMA16(al, bh, c); return c;
}

__device__ __forceinline__ float dot64(const float* __restrict__ a, const float* __restrict__ w){
  const float4* a4 = (const float4*)a;
  const float4* w4 = (const float4*)w;
  float acc = 0.f;
  #pragma unroll
  for (int k = 0; k < 16; ++k){ float4 x = a4[k], y = w4[k];
    acc += x.x*y.x + x.y*y.y + x.z*y.z + x.w*y.w; }
  return acc;
}
__device__ __forceinline__ float dot16(const float* __restrict__ a, const float* __restrict__ b){
  const float4* a4 = (const float4*)a; const float4* b4 = (const float4*)b;
  float acc = 0.f;
  #pragma unroll
  for (int k = 0; k < 4; ++k){ float4 x = a4[k], y = b4[k];
    acc += x.x*y.x + x.y*y.y + x.z*y.z + x.w*y.w; }
  return acc;
}

// pack A-frags (16 tokens x 64 k) from stride-68 LDS buffer into fragA (hi[128], lo[128])
__device__ __forceinline__ void packA68(const float* buf, short8* fA, int tid){
  if (tid < 128){
    int ln = tid & 63, ks = tid >> 6;
    const float* r = buf + (ln & 15)*68 + ks*32 + ((ln >> 4) & 3)*8;
    short8 hi, lo; split8(r, hi, lo);
    fA[tid] = hi; fA[128 + tid] = lo;
  }
}

// -------------------------------------------------------------------------
// Prep: convert ALL weight matrices to MFMA B-fragment pool (hi at [s], lo at
// [FRAG_TOT+s]; lo only written for attn segments — ttcn + FF consume hi only).
// B[k][n]: n = nt*16 + (lane&15), k = ks*32 + quad*8 + j.
// w3 special: (a) columns reordered so tile nt covers i = nt>>2 (constant per
// tile), t = (nt&3)*16 + lane&15; (b) k=63 slot = 1.0 (mask carrier);
// (c) ALL w3 values scaled by log2(e) so epilogue uses raw v_exp_f32.
// -------------------------------------------------------------------------
__global__ __launch_bounds__(256) void prep_kernel(
    const float* __restrict__ w1, const float* __restrict__ w2, const float* __restrict__ w3,
    const float* __restrict__ gqw, const float* __restrict__ gkw,
    const float* __restrict__ gvw, const float* __restrict__ gow,
    const float* __restrict__ inw, const float* __restrict__ outw,
    const float* __restrict__ fw1, const float* __restrict__ fw2,
    uint4* __restrict__ fr)
{
  int s = blockIdx.x*256 + threadIdx.x;
  if (s >= FRAG_TOT) return;
  const float* src; int Nr, Kr, KS, rel; int w3seg = 0, noLo = 0;
  if (s < 256)      { src = w1; Nr=63;  Kr=17; KS=1; rel = s; noLo = 1; }
  else if (s < 768) { src = w2; Nr=63;  Kr=63; KS=2; rel = s-256; noLo = 1; }
  else if (s < 9472){ src = w3; Nr=1071;Kr=63; KS=2; rel = s-768; w3seg = 1; noLo = 1; }
  else {
    int t = s - 9472, l = t / 36864, r2 = t - l*36864;
    if (r2 < 512)        { src = gqw + l*4096;   Nr=64;  Kr=64;   KS=2;  rel = r2; }
    else if (r2 < 1024)  { src = gkw + l*4096;   Nr=64;  Kr=64;   KS=2;  rel = r2-512; }
    else if (r2 < 1536)  { src = gvw + l*4096;   Nr=64;  Kr=64;   KS=2;  rel = r2-1024; }
    else if (r2 < 2048)  { src = gow + l*4096;   Nr=64;  Kr=64;   KS=2;  rel = r2-1536; }
    else if (r2 < 3584)  { src = inw + l*12288;  Nr=192; Kr=64;   KS=2;  rel = r2-2048; }
    else if (r2 < 4096)  { src = outw + l*4096;  Nr=64;  Kr=64;   KS=2;  rel = r2-3584; }
    else if (r2 < 20480) { src = fw1 + l*131072; Nr=2048;Kr=64;   KS=2;  rel = r2-4096; noLo = 1; }
    else                 { src = fw2 + l*131072; Nr=64;  Kr=2048; KS=64; rel = r2-20480; noLo = 1; }
  }
  int lane = rel & 63, tmp = rel >> 6;
  int ks = tmp % KS, nt = tmp / KS;
  int kb = ks*32 + ((lane >> 4) & 3)*8;
  int n, validn;
  if (w3seg){
    int i = nt >> 2, tq = nt & 3;
    int t = tq*16 + (lane & 15);
    n = t*17 + i;                         // source row of w3 (c = t*17+i)
    validn = (t < 63);
  } else {
    n = nt*16 + (lane & 15);
    validn = (n < Nr);
  }
  float v[8];
  #pragma unroll
  for (int j = 0; j < 8; ++j){
    v[j] = (validn && (kb + j) < Kr) ? src[n*Kr + kb + j] : 0.f;
    if (w3seg){
      if ((kb + j) == 63) v[j] = 1.0f;               // mask-carrier column
      v[j] *= 1.4426950408889634f;                   // log2(e) for exp2 epilogue
    }
  }
  ushort_t hh[8];
  #pragma unroll
  for (int j = 0; j < 8; ++j) hh[j] = f2bf(v[j]);
  fr[s] = pack8(hh);
  if (!noLo){
    ushort_t ll[8];
    #pragma unroll
    for (int j = 0; j < 8; ++j) ll[j] = f2bf(v[j] - bf2f(hh[j]));
    fr[FRAG_TOT + s] = pack8(ll);
  }
}

// -------------------------------------------------------------------------
// Fused TTCN — bf16 1-term MFMA, h1/h2 stored directly as bf16 [l][t].
// P6 epilogue accumulates h_t in-register (t_out loop-invariant, i = it).
// -------------------------------------------------------------------------
__global__ __launch_bounds__(256) void ttcn_kernel(
    const float* __restrict__ x, const int* __restrict__ mask,
    const float* __restrict__ b1, const float* __restrict__ b2,
    const float* __restrict__ tb,
    const short8* __restrict__ w1bhi,
    const short8* __restrict__ w2bhi,
    const short8* __restrict__ w3bhi,
    float* __restrict__ xp, float* __restrict__ pm)
{
  __shared__ __align__(16) char pool[16512];
  float*    xs    = (float*)(pool + 0);        // 32x20 f (row l, stride 20)
  float*    xst   = (float*)(pool + 2560);     // 17x36 f (row i, stride 36)
  float*    msv   = (float*)(pool + 5008);     // 32 f
  float*    xsumv = (float*)(pool + 5136);     // 17 f (+pad)
  short8*   xfhi  = (short8*)(pool + 5216);    // 128 slots
  ushort_t* h1t   = (ushort_t*)(pool + 7264);  // 32x72 bf16 [l][t] (dead after P4)
  ushort_t* h2t   = (ushort_t*)(pool + 11872); // 32x72 bf16 [l][t]

  const int p = blockIdx.x, tid = threadIdx.x;
  const int lane = tid & 63, wvi = tid >> 6;
  const int nidx = lane & 15, quad = lane >> 4;

  // P0: stage x (stride 20) + mask
  for (int idx = tid; idx < LX*IN_DIM_; idx += 256){
    int l = (idx * 3856) >> 16;             // idx/17 exact for idx<1088
    int i = idx - l*17;
    xs[l*20 + i] = x[p*(LX*IN_DIM_) + idx];
  }
  if (tid < LX) msv[tid] = (float)mask[p*LX + tid];
  __syncthreads();

  // P1: x A-fragments (hi only) on threads <128; xsumv + xst on the rest
  if (tid < 128){
    int mt = tid >> 6;
    int l = mt*16 + nidx;
    float r[8];
    #pragma unroll
    for (int j = 0; j < 8; ++j){
      int k = quad*8 + j;
      r[j] = (k < IN_DIM_) ? xs[l*20 + k] : 0.f;
    }
    ((uint4*)xfhi)[tid] = cvt8(r);
  } else {
    if (tid < 128 + IN_DIM_){
      int i = tid - 128;
      float s = 0.f;
      #pragma unroll
      for (int l = 0; l < LX; ++l) s += xs[l*20 + i];
      xsumv[i] = s;
    }
    for (int idx = tid - 128; idx < 544; idx += 128){
      int i = idx >> 5, l = idx & 31;
      xst[i*36 + l] = xs[l*20 + i];
    }
  }
  __syncthreads();

  // P2: GEMM1  h1 = relu(x @ w1^T + b1) -> bf16 [l][t] stride 72
  {
    short8 axh0 = xfhi[lane], axh1 = xfhi[64 + lane];
    short8 bh = w1bhi[wvi*64 + lane];
    floatx4 a0 = {0.f,0.f,0.f,0.f}, a1 = {0.f,0.f,0.f,0.f};
    a0 = MFMA16(axh0, bh, a0);
    a1 = MFMA16(axh1, bh, a1);
    int t = wvi*16 + nidx;
    float bb = (t < TT_) ? b1[t] : 0.f;
    #pragma unroll
    for (int r = 0; r < 4; ++r){
      h1t[(quad*4+r)*72 + t]      = f2bf(fmaxf(a0[r] + bb, 0.f));
      h1t[(16+quad*4+r)*72 + t]   = f2bf(fmaxf(a1[r] + bb, 0.f));
    }
  }
  __syncthreads();

  // P4: GEMM2  h2 = relu(h1 @ w2^T + b2); A-frags = direct b128 from h1t
  {
    short8 ah[2][2];
    #pragma unroll
    for (int mt = 0; mt < 2; ++mt)
      #pragma unroll
      for (int ks = 0; ks < 2; ++ks){
        int l = mt*16 + nidx;
        ah[mt][ks] = *(const short8*)((const char*)h1t + (l*72 + ks*32 + quad*8)*2);
      }
    short8 bh0 = w2bhi[(wvi*2+0)*64 + lane];
    short8 bh1 = w2bhi[(wvi*2+1)*64 + lane];
    floatx4 a0 = {0.f,0.f,0.f,0.f}, a1 = {0.f,0.f,0.f,0.f};
    a0 = MFMA16(ah[0][0], bh0, a0); a0 = MFMA16(ah[0][1], bh1, a0);
    a1 = MFMA16(ah[1][0], bh0, a1); a1 = MFMA16(ah[1][1], bh1, a1);
    int t = wvi*16 + nidx;
    float bb = (t < TT_) ? b2[t] : 0.f;
    #pragma unroll
    for (int r = 0; r < 4; ++r){
      h2t[(quad*4+r)*72 + t]      = f2bf(fmaxf(a0[r] + bb, 0.f));
      h2t[(16+quad*4+r)*72 + t]   = f2bf(fmaxf(a1[r] + bb, 0.f));
    }
  }
  __syncthreads();

  // P6: GEMM3 (i-major tiles; mask + log2e folded into MFMA) + softmax +
  // contract + in-register h_t accumulation (P7 fused: i = it, t_out fixed)
  {
    short8 ah[2][2];
    #pragma unroll
    for (int mt = 0; mt < 2; ++mt)
      #pragma unroll
      for (int ks = 0; ks < 2; ++ks){
        int l = mt*16 + nidx;
        ah[mt][ks] = *(const short8*)((const char*)h2t + (l*72 + ks*32 + quad*8)*2);
      }
    // mask carrier: A[l][63] = -1e8 (bf16) for masked l; w3 B[63][*] = log2e
    if (quad == 3){
      ah[0][1][7] = (short)((msv[nidx]      == 0.f) ? f2bf(-1e8f) : (ushort_t)0);
      ah[1][1][7] = (short)((msv[16 + nidx] == 0.f) ? f2bf(-1e8f) : (ushort_t)0);
    }
    const int t_out = wvi*16 + nidx;          // constant per lane
    const int rA = quad*4;
    float acc_t = 0.f;                        // running sum over i (quad 0 uses)
    short8 nbh0 = w3bhi[(wvi*2+0)*64 + lane];
    short8 nbh1 = w3bhi[(wvi*2+1)*64 + lane];
    for (int it = 0; it < 17; ++it){
      short8 bh0 = nbh0, bh1 = nbh1;
      if (it < 16){
        int nt = wvi + it*4 + 4;
        nbh0 = w3bhi[(nt*2+0)*64 + lane];
        nbh1 = w3bhi[(nt*2+1)*64 + lane];
      }
      floatx4 a0 = {0.f,0.f,0.f,0.f}, a1 = {0.f,0.f,0.f,0.f};
      a0 = MFMA16(ah[0][0], bh0, a0); a0 = MFMA16(ah[0][1], bh1, a0);
      a1 = MFMA16(ah[1][0], bh0, a1); a1 = MFMA16(ah[1][1], bh1, a1);

      const float4 xA = *(const float4*)(xst + it*36 + rA);
      const float4 xB = *(const float4*)(xst + it*36 + rA + 16);
      float den0 = 0.f, den1 = 0.f, num0 = 0.f, num1 = 0.f;
      float e;
      e = fast_exp2(a0[0]); den0 += e; num0 = fmaf(e, xA.x, num0);
      e = fast_exp2(a0[1]); den0 += e; num0 = fmaf(e, xA.y, num0);
      e = fast_exp2(a0[2]); den0 += e; num0 = fmaf(e, xA.z, num0);
      e = fast_exp2(a0[3]); den0 += e; num0 = fmaf(e, xA.w, num0);
      e = fast_exp2(a1[0]); den1 += e; num1 = fmaf(e, xB.x, num1);
      e = fast_exp2(a1[1]); den1 += e; num1 = fmaf(e, xB.y, num1);
      e = fast_exp2(a1[2]); den1 += e; num1 = fmaf(e, xB.z, num1);
      e = fast_exp2(a1[3]); den1 += e; num1 = fmaf(e, xB.w, num1);
      float den = den0 + den1, num = num0 + num1;
      den += __shfl_xor(den, 16, 64); den += __shfl_xor(den, 32, 64);
      num += __shfl_xor(num, 16, 64); num += __shfl_xor(num, 32, 64);
      float res = (den > 0.f) ? num * fast_rcp(den) : xsumv[it] * (1.f/32.f);
      acc_t += res;
    }
    if (quad == 0 && t_out < TT_)
      xp[p*D_ + t_out] = fmaxf(acc_t + tb[t_out], 0.f);
  }
  if (tid == 63){
    float s = 0.f;
    #pragma unroll
    for (int l = 0; l < LX; ++l) s += msv[l];
    float mp = (s > 0.f) ? 1.f : 0.f;
    xp[p*D_ + TT_] = mp;
    pm[p] = mp;
  }
}

// -------------------------------------------------------------------------
// BOTH transformer layers fused, one block per bn — 256 threads (best
// measured config, R11): register cross-phase prefetch for all B-frags,
// merged score+softmax, 64-thread shfl LN.
// -------------------------------------------------------------------------
__global__ __launch_bounds__(256) void layer12_kernel(
    const float* __restrict__ xin, const float* __restrict__ pm,
    const short8* __restrict__ frS,
    const float* __restrict__ gqb, const float* __restrict__ gkb,
    const float* __restrict__ gvb, const float* __restrict__ gob,
    const float* __restrict__ inb, const float* __restrict__ outb,
    const float* __restrict__ ln1g, const float* __restrict__ ln1b,
    const float* __restrict__ fb1, const float* __restrict__ fb2,
    const float* __restrict__ ln2g, const float* __restrict__ ln2b,
    float* __restrict__ xout)
{
  __shared__ __align__(16) float xb[16*68];
  __shared__ __align__(16) float xb2[16*68];
  __shared__ __align__(16) float q_[16*68];
  __shared__ __align__(16) float k_[16*68];
  __shared__ __align__(16) float v_[16*68];
  __shared__ __align__(16) float ao[16*68];
  __shared__ __align__(16) float ss[1024];
  __shared__ __align__(16) short8 fragA[256];
  __shared__ __align__(16) float hbuf[4*16*36];
  __shared__ __align__(16) float part[4*16*68];
  __shared__ __align__(16) float pe_t[1024];
  __shared__ float tbt[16];
  __shared__ float pmv[16], mur[16], rvr[16];

  const int bn = blockIdx.x, tid = threadIdx.x;
  const int lane = tid & 63, wvi = tid >> 6;
  const int nidx = lane & 15, quad = lane >> 4;
  const float* xin_p = xin + bn*1024;

  for (int o = tid; o < 1024; o += 256) xb[(o>>6)*68 + (o&63)] = xin_p[o];
  if (tid < 16) pmv[tid] = pm[bn*16 + tid];
  for (int o = tid; o < 1024; o += 256){
    int tok = o >> 6, d = o & 63;
    float div = __expf((float)(d & ~1) * (-0.14391156831212793f)); // -ln(1e4)/64
    float arg = (float)tok * div;
    pe_t[o] = (d & 1) ? cosf(arg) : sinf(arg);
  }
  if (tid >= 32 && tid < 48) tbt[tid-32] = logf(expf(-5.0f*(float)(tid-32)) + 1e-12f);
  __syncthreads();

  for (int l = 0; l < 2; ++l){
    const int lbase = 9472 + l*36864;
    const float* gqbL = gqb + l*64;  const float* gkbL = gkb + l*64;
    const float* gvbL = gvb + l*64;  const float* gobL = gob + l*64;
    const float* inbL = inb + l*192; const float* outbL = outb + l*64;
    const float* ln1gL = ln1g + l*64; const float* ln1bL = ln1b + l*64;
    const float* fb1L = fb1 + l*2048; const float* fb2L = fb2 + l*64;
    const float* ln2gL = ln2g + l*64; const float* ln2bL = ln2b + l*64;

    // save layer input for the l==1 residual
    float xres[4];
    #pragma unroll
    for (int kk2 = 0; kk2 < 4; ++kk2){
      int o = tid + kk2*256;
      xres[kk2] = xb[(o>>6)*68 + (o&63)];
    }

    // ================= PREFETCH WAVE 1: QKV(12) + gattn-out(4) + MHA-in(12)
    short8 gb[3][4], ob4[4], mb[3][4];
    #pragma unroll
    for (int mat = 0; mat < 3; ++mat){
      int base = lbase + mat*512;
      gb[mat][0] = frS[base + (wvi*2+0)*64 + lane];
      gb[mat][1] = frS[FRAG_TOT + base + (wvi*2+0)*64 + lane];
      gb[mat][2] = frS[base + (wvi*2+1)*64 + lane];
      gb[mat][3] = frS[FRAG_TOT + base + (wvi*2+1)*64 + lane];
    }
    {
      int base = lbase + 1536;   // gow
      ob4[0] = frS[base + (wvi*2+0)*64 + lane];
      ob4[1] = frS[FRAG_TOT + base + (wvi*2+0)*64 + lane];
      ob4[2] = frS[base + (wvi*2+1)*64 + lane];
      ob4[3] = frS[FRAG_TOT + base + (wvi*2+1)*64 + lane];
    }
    #pragma unroll
    for (int sel = 0; sel < 3; ++sel){
      int base = lbase + OFF_INW + (sel*4 + wvi)*128;
      mb[sel][0] = frS[base + lane];
      mb[sel][1] = frS[FRAG_TOT + base + lane];
      mb[sel][2] = frS[base + 64 + lane];
      mb[sel][3] = frS[FRAG_TOT + base + 64 + lane];
    }

    // ---- gattn QKV ----
    packA68(xb, fragA, tid);
    __syncthreads();
    {
      short8 axh0 = fragA[lane], axh1 = fragA[64+lane];
      short8 axl0 = fragA[128+lane], axl1 = fragA[192+lane];
      #pragma unroll
      for (int mat = 0; mat < 3; ++mat){
        floatx4 c = {0.f,0.f,0.f,0.f};
        c = mm3(axh0, axl0, gb[mat][0], gb[mat][1], c);
        c = mm3(axh1, axl1, gb[mat][2], gb[mat][3], c);
        int d = wvi*16 + nidx;
        float bb = (mat == 0 ? gqbL : mat == 1 ? gkbL : gvbL)[d];
        float* dst = (mat == 0 ? q_ : mat == 1 ? k_ : v_);
        #pragma unroll
        for (int r = 0; r < 4; ++r) dst[(quad*4+r)*68 + d] = c[r] + bb;
      }
    }
    __syncthreads();
    // ---- merged scores+softmax (row per 4-lane group) ----
    {
      int row = tid >> 2;                 // h*16+qm
      int h = row >> 4, qm = row & 15;
      int km0 = (tid & 3) * 4;
      float s4[4];
      #pragma unroll
      for (int j = 0; j < 4; ++j){
        int km = km0 + j;
        float acc = dot16(q_ + qm*68 + h*16, k_ + km*68 + h*16);
        int dd = qm - km; if (dd < 0) dd = -dd;
        acc = acc * 0.25f + tbt[dd];
        if (pmv[km] == 0.f) acc = -1e9f;
        s4[j] = acc;
      }
      float mx = fmaxf(fmaxf(s4[0], s4[1]), fmaxf(s4[2], s4[3]));
      mx = fmaxf(mx, __shfl_xor(mx, 1, 64));
      mx = fmaxf(mx, __shfl_xor(mx, 2, 64));
      float e4[4], se = 0.f;
      #pragma unroll
      for (int j = 0; j < 4; ++j){ e4[j] = __expf(s4[j]-mx); se += e4[j]; }
      se += __shfl_xor(se, 1, 64);
      se += __shfl_xor(se, 2, 64);
      float inv = fast_rcp(se);
      #pragma unroll
      for (int j = 0; j < 4; ++j) ss[row*16 + km0 + j] = e4[j]*inv;
    }
    __syncthreads();
    for (int o = tid; o < 1024; o += 256){
      int m = o >> 6, d = o & 63, h = d >> 4;
      float acc = 0.f;
      #pragma unroll
      for (int km = 0; km < 16; ++km) acc += ss[h*256 + m*16 + km] * v_[km*68 + d];
      ao[m*68 + d] = acc;
    }
    __syncthreads();
    packA68(ao, fragA, tid);
    __syncthreads();
    {
      short8 axh0 = fragA[lane], axh1 = fragA[64+lane];
      short8 axl0 = fragA[128+lane], axl1 = fragA[192+lane];
      floatx4 c = {0.f,0.f,0.f,0.f};
      c = mm3(axh0, axl0, ob4[0], ob4[1], c);
      c = mm3(axh1, axl1, ob4[2], ob4[3], c);
      int d = wvi*16 + nidx;
      float bb = gobL[d];
      #pragma unroll
      for (int r = 0; r < 4; ++r){
        int tok = quad*4 + r;
        xb[tok*68 + d] += (c[r] + bb) * pmv[tok] + pe_t[tok*64 + d];
      }
    }
    __syncthreads();

    // ================= PREFETCH WAVE 2: MHA-out(4) + FF f1/f2 initial (8)
    short8 mob[4], f1c[4], f2c[4];
    {
      int base = lbase + OFF_OUTW;
      mob[0] = frS[base + (wvi*2+0)*64 + lane];
      mob[1] = frS[FRAG_TOT + base + (wvi*2+0)*64 + lane];
      mob[2] = frS[base + (wvi*2+1)*64 + lane];
      mob[3] = frS[FRAG_TOT + base + (wvi*2+1)*64 + lane];
    }
    {
      int f1base = lbase + OFF_FW1, f2base = lbase + OFF_FW2;
      #pragma unroll
      for (int t2 = 0; t2 < 2; ++t2){
        int sb = f1base + ((wvi*32+t2)*2)*64 + lane;
        f1c[t2*2+0] = frS[sb];
        f1c[t2*2+1] = frS[sb + 64];
      }
      #pragma unroll
      for (int ntd = 0; ntd < 4; ++ntd)
        f2c[ntd] = frS[f2base + (ntd*64 + wvi*16)*64 + lane];
    }

    // ---- MHA QKV (frags prefetched) ----
    packA68(xb, fragA, tid);
    __syncthreads();
    {
      short8 axh0 = fragA[lane], axh1 = fragA[64+lane];
      short8 axl0 = fragA[128+lane], axl1 = fragA[192+lane];
      #pragma unroll
      for (int sel = 0; sel < 3; ++sel){
        floatx4 c = {0.f,0.f,0.f,0.f};
        c = mm3(axh0, axl0, mb[sel][0], mb[sel][1], c);
        c = mm3(axh1, axl1, mb[sel][2], mb[sel][3], c);
        int d = wvi*16 + nidx;
        float bb = inbL[(sel*4 + wvi)*16 + nidx];
        float* dst = (sel == 0 ? q_ : sel == 1 ? k_ : v_);
        #pragma unroll
        for (int r = 0; r < 4; ++r) dst[(quad*4+r)*68 + d] = c[r] + bb;
      }
    }
    __syncthreads();
    {
      int row = tid >> 2;
      int h = row >> 4, qm = row & 15;
      int km0 = (tid & 3) * 4;
      float s4[4];
      #pragma unroll
      for (int j = 0; j < 4; ++j)
        s4[j] = 0.25f * dot16(q_ + qm*68 + h*16, k_ + (km0+j)*68 + h*16);
      float mx = fmaxf(fmaxf(s4[0], s4[1]), fmaxf(s4[2], s4[3]));
      mx = fmaxf(mx, __shfl_xor(mx, 1, 64));
      mx = fmaxf(mx, __shfl_xor(mx, 2, 64));
      float e4[4], se = 0.f;
      #pragma unroll
      for (int j = 0; j < 4; ++j){ e4[j] = __expf(s4[j]-mx); se += e4[j]; }
      se += __shfl_xor(se, 1, 64);
      se += __shfl_xor(se, 2, 64);
      float inv = fast_rcp(se);
      #pragma unroll
      for (int j = 0; j < 4; ++j) ss[row*16 + km0 + j] = e4[j]*inv;
    }
    __syncthreads();
    for (int o = tid; o < 1024; o += 256){
      int m = o >> 6, d = o & 63, h = d >> 4;
      float acc = 0.f;
      #pragma unroll
      for (int km = 0; km < 16; ++km) acc += ss[h*256 + m*16 + km] * v_[km*68 + d];
      ao[m*68 + d] = acc;
    }
    __syncthreads();
    packA68(ao, fragA, tid);
    __syncthreads();
    {
      short8 axh0 = fragA[lane], axh1 = fragA[64+lane];
      short8 axl0 = fragA[128+lane], axl1 = fragA[192+lane];
      floatx4 c = {0.f,0.f,0.f,0.f};
      c = mm3(axh0, axl0, mob[0], mob[1], c);
      c = mm3(axh1, axl1, mob[2], mob[3], c);
      int d = wvi*16 + nidx;
      float bb = outbL[d];
      #pragma unroll
      for (int r = 0; r < 4; ++r) xb[(quad*4+r)*68 + d] += c[r] + bb;
    }
    __syncthreads();

    // ---- LN1 (64 threads, 4 lanes/row) -> xb2 ----
    if (tid < 64){
      int row = tid >> 2, seg = tid & 3;
      const float* rp = xb + row*68 + seg*16;
      float s = 0.f;
      #pragma unroll
      for (int j = 0; j < 16; ++j) s += rp[j];
      s += __shfl_xor(s, 1, 64); s += __shfl_xor(s, 2, 64);
      float mu = s * (1.f/64.f);
      float v = 0.f;
      #pragma unroll
      for (int j = 0; j < 16; ++j){ float t = rp[j]-mu; v += t*t; }
      v += __shfl_xor(v, 1, 64); v += __shfl_xor(v, 2, 64);
      if (seg == 0){ mur[row] = mu; rvr[row] = rsqrtf(v*(1.f/64.f) + 1e-5f); }
    }
    __syncthreads();
    for (int o = tid; o < 1024; o += 256){
      int m = o >> 6, d = o & 63;
      xb2[m*68 + d] = (xb[m*68 + d] - mur[m]) * rvr[m] * ln1gL[d] + ln1bL[d];
    }
    __syncthreads();
    packA68(xb2, fragA, tid);
    __syncthreads();

    // ---- FF (2048 hidden): 1-term bf16; f1 & f2 both prefetched 1 iter ahead
    {
      const int w = wvi;
      const int f1base = lbase + OFF_FW1, f2base = lbase + OFF_FW2;
      short8 axh0 = fragA[lane], axh1 = fragA[64 + lane];
      floatx4 y0 = {0.f,0.f,0.f,0.f}, y1 = y0, y2 = y0, y3 = y0;
      float* hw = hbuf + w*576;

      short8 f1n[4], f2n[4];
      for (int it = 0; it < 16; ++it){
        int ntA = w*32 + it*2;
        floatx4 hA = {0.f,0.f,0.f,0.f}, hB = hA;
        hA = MFMA16(axh0, f1c[0], hA); hA = MFMA16(axh1, f1c[1], hA);
        hB = MFMA16(axh0, f1c[2], hB); hB = MFMA16(axh1, f1c[3], hB);
        float bbA = fb1L[ntA*16 + nidx], bbB = fb1L[ntA*16 + 16 + nidx];
        #pragma unroll
        for (int r = 0; r < 4; ++r){
          hw[(quad*4+r)*36 + nidx]      = fmaxf(hA[r] + bbA, 0.f);
          hw[(quad*4+r)*36 + 16 + nidx] = fmaxf(hB[r] + bbB, 0.f);
        }
        if (it < 15){
          int ntN = ntA + 2, kstN = w*16 + it + 1;
          #pragma unroll
          for (int t2 = 0; t2 < 2; ++t2){
            int sb = f1base + ((ntN+t2)*2)*64 + lane;
            f1n[t2*2+0] = frS[sb];
            f1n[t2*2+1] = frS[sb + 64];
          }
          #pragma unroll
          for (int ntd = 0; ntd < 4; ++ntd)
            f2n[ntd] = frS[f2base + (ntd*64 + kstN)*64 + lane];
        }
        short8 ah = cvt8s(hw + (lane & 15)*36 + quad*8);
        y0 = MFMA16(ah, f2c[0], y0);
        y1 = MFMA16(ah, f2c[1], y1);
        y2 = MFMA16(ah, f2c[2], y2);
        y3 = MFMA16(ah, f2c[3], y3);
        #pragma unroll
        for (int j = 0; j < 4; ++j){ f1c[j] = f1n[j]; f2c[j] = f2n[j]; }
      }
      #pragma unroll
      for (int r = 0; r < 4; ++r){
        int row = (quad*4 + r)*68;
        part[w*1088 + row + nidx]      = y0[r];
        part[w*1088 + row + 16 + nidx] = y1[r];
        part[w*1088 + row + 32 + nidx] = y2[r];
        part[w*1088 + row + 48 + nidx] = y3[r];
      }
    }
    __syncthreads();
    for (int o = tid; o < 1024; o += 256){
      int tok = o >> 6, d = o & 63;
      float s = xb2[tok*68 + d] + fb2L[d];
      #pragma unroll
      for (int ww = 0; ww < 4; ++ww) s += part[ww*1088 + tok*68 + d];
      xb[tok*68 + d] = s;
    }
    __syncthreads();
    // ---- LN2 (64 threads) + layer-1 residual ----
    if (tid < 64){
      int row = tid >> 2, seg = tid & 3;
      const float* rp = xb + row*68 + seg*16;
      float s = 0.f;
      #pragma unroll
      for (int j = 0; j < 16; ++j) s += rp[j];
      s += __shfl_xor(s, 1, 64); s += __shfl_xor(s, 2, 64);
      float mu = s * (1.f/64.f);
      float v = 0.f;
      #pragma unroll
      for (int j = 0; j < 16; ++j){ float t = rp[j]-mu; v += t*t; }
      v += __shfl_xor(v, 1, 64); v += __shfl_xor(v, 2, 64);
      if (seg == 0){ mur[row] = mu; rvr[row] = rsqrtf(v*(1.f/64.f) + 1e-5f); }
    }
    __syncthreads();
    #pragma unroll
    for (int kk2 = 0; kk2 < 4; ++kk2){
      int o = tid + kk2*256;
      int tok = o >> 6, d = o & 63;
      float vv = (xb[tok*68 + d] - mur[tok]) * rvr[tok] * ln2gL[d] + ln2bL[d];
      if (l == 0) xb[tok*68 + d] = vv;                 // becomes layer-1 input
      else        xout[bn*1024 + o] = vv + xres[kk2];  // layer residual
    }
    __syncthreads();
  }
}

// -------------------------------------------------------------------------
// Classifier head. One block per b. (small; fp32)
// -------------------------------------------------------------------------
__global__ __launch_bounds__(256) void final_kernel(
    const float* __restrict__ xc, const float* __restrict__ pm,
    const float* __restrict__ q_embed,
    const float* __restrict__ cin_w, const float* __restrict__ cin_b,
    const float* __restrict__ cout_w, const float* __restrict__ cout_b,
    const float* __restrict__ logit_w, const float* __restrict__ logit_b,
    float* __restrict__ out)
{
  const int b = blockIdx.x;
  const int tid = threadIdx.x;
  __shared__ __align__(16) float xs[M_ * D_];
  __shared__ float kpmv[M_];
  __shared__ __align__(16) float qv[5 * D_], kv[M_ * D_], vv[M_ * D_];
  __shared__ float sv[H_ * 5 * M_];
  __shared__ __align__(16) float ao[5 * D_], zv[5 * D_];

  for (int o = tid; o < M_ * D_; o += 256) {
    int m = o >> 6, d = o & 63;
    float acc = 0.f;
    #pragma unroll
    for (int n = 0; n < N_; ++n) acc += xc[(((b * N_ + n) * M_ + m) * D_) + d];
    xs[o] = acc * (1.f / 32.f);
  }
  if (tid < M_) {
    float any = 0.f;
    #pragma unroll
    for (int n = 0; n < N_; ++n) any += (pm[(b * N_ + n) * M_ + tid] > 0.f) ? 1.f : 0.f;
    kpmv[tid] = (any > 0.f) ? 0.f : 1.f;
  }
  __syncthreads();

  for (int o = tid; o < 5 * D_; o += 256) {
    int qi = o >> 6, d = o & 63;
    qv[o] = cin_b[d] + dot64(q_embed + qi * D_, cin_w + d * D_);
  }
  for (int o = tid; o < 2 * M_ * D_; o += 256) {
    int sel = o >> 10, r = o & 1023, m = r >> 6, d = r & 63;
    float acc = cin_b[D_ + sel * D_ + d] + dot64(xs + m * D_, cin_w + (D_ + sel * D_ + d) * D_);
    ((sel == 0) ? kv : vv)[r] = acc;
  }
  __syncthreads();

  for (int o = tid; o < H_ * 5 * M_; o += 256) {
    int h = o / 80, r = o % 80, qi = r >> 4, km = r & 15;
    float acc = 0.25f * dot16(qv + qi * D_ + h * DH_, kv + km * D_ + h * DH_);
    if (kpmv[km] != 0.f) acc = -1e9f;
    sv[o] = acc;
  }
  __syncthreads();
  if (tid < H_ * 5) {
    int h = tid / 5, qi = tid % 5;
    float* row = sv + h * 80 + qi * M_;
    float mx = -1e30f;
    #pragma unroll
    for (int km = 0; km < M_; ++km) mx = fmaxf(mx, row[km]);
    float se = 0.f;
    #pragma unroll
    for (int km = 0; km < M_; ++km) { float e = __expf(row[km] - mx); row[km] = e; se += e; }
    float inv = 1.f / se;
    #pragma unroll
    for (int km = 0; km < M_; ++km) row[km] *= inv;
  }
  __syncthreads();
  for (int o = tid; o < 5 * D_; o += 256) {
    int qi = o >> 6, d = o & 63, h = d >> 4;
    float acc = 0.f;
    #pragma unroll
    for (int km = 0; km < M_; ++km) acc += sv[h * 80 + qi * M_ + km] * vv[km * D_ + d];
    ao[o] = acc;
  }
  __syncthreads();
  for (int o = tid; o < 5 * D_; o += 256) {
    int qi = o >> 6, d = o & 63;
    zv[o] = cout_b[d] + dot64(ao + qi * D_, cout_w + d * D_);
  }
  __syncthreads();
  if (tid < 5) {
    float acc = logit_b[0] + dot64(zv + tid * D_, logit_w);
    out[b * 5 + tid] = acc;
  }
}

// -------------------------------------------------------------------------
extern "C" void kernel_launch(void* const* d_in, const int* in_sizes, int n_in,
                              void* d_out, int out_size, void* d_ws, size_t ws_size,
                              hipStream_t stream) {
  const float* x       = (const float*)d_in[0];
  const int*   mask    = (const int*)  d_in[1];
  const float* ttcn_w1 = (const float*)d_in[2];
  const float* ttcn_b1 = (const float*)d_in[3];
  const float* ttcn_w2 = (const float*)d_in[4];
  const float* ttcn_b2 = (const float*)d_in[5];
  const float* ttcn_w3 = (const float*)d_in[6];
  const float* ttcn_b3 = (const float*)d_in[7];   // unused: cancels in softmax
  const float* t_bias  = (const float*)d_in[8];
  const float* ga_qw   = (const float*)d_in[9];
  const float* ga_qb   = (const float*)d_in[10];
  const float* ga_kw   = (const float*)d_in[11];
  const float* ga_kb   = (const float*)d_in[12];
  const float* ga_vw   = (const float*)d_in[13];
  const float* ga_vb   = (const float*)d_in[14];
  const float* ga_ow   = (const float*)d_in[15];
  const float* ga_ob   = (const float*)d_in[16];
  const float* tf_in_w = (const float*)d_in[17];
  const float* tf_in_b = (const float*)d_in[18];
  const float* tf_out_w= (const float*)d_in[19];
  const float* tf_out_b= (const float*)d_in[20];
  const float* tf_ln1g = (const float*)d_in[21];
  const float* tf_ln1b = (const float*)d_in[22];
  const float* tf_ln2g = (const float*)d_in[23];
  const float* tf_ln2b = (const float*)d_in[24];
  const float* tf_fw1  = (const float*)d_in[25];
  const float* tf_fb1  = (const float*)d_in[26];
  const float* tf_fw2  = (const float*)d_in[27];
  const float* tf_fb2  = (const float*)d_in[28];
  const float* q_embed = (const float*)d_in[29];
  const float* cls_in_w  = (const float*)d_in[30];
  const float* cls_in_b  = (const float*)d_in[31];
  const float* cls_out_w = (const float*)d_in[32];
  const float* cls_out_b = (const float*)d_in[33];
  const float* logit_w = (const float*)d_in[34];
  const float* logit_b = (const float*)d_in[35];
  (void)ttcn_b3;

  float* wsf  = (float*)d_ws;
  float* xp   = wsf;                        // 262144 f
  float* pmb  = wsf + P_TOT * D_;           // 4096 f
  float* xbuf = pmb + P_TOT;                // 262144 f
  uint4* fr   = (uint4*)(xbuf + P_TOT * D_);// 2*FRAG_TOT uint4
  const short8* frS = (const short8*)fr;

  prep_kernel<<<325, 256, 0, stream>>>(ttcn_w1, ttcn_w2, ttcn_w3,
      ga_qw, ga_kw, ga_vw, ga_ow, tf_in_w, tf_out_w, tf_fw1, tf_fw2, fr);

  ttcn_kernel<<<P_TOT, 256, 0, stream>>>(x, mask, ttcn_b1, ttcn_b2, t_bias,
      frS + 0, frS + 256, frS + 768,
      xp, pmb);

  layer12_kernel<<<BN_, 256, 0, stream>>>(xp, pmb, frS,
      ga_qb, ga_kb, ga_vb, ga_ob, tf_in_b, tf_out_b, tf_ln1g, tf_ln1b,
      tf_fb1, tf_fb2, tf_ln2g, tf_ln2b, xbuf);

  final_kernel<<<B_, 256, 0, stream>>>(xbuf, pmb, q_embed,
                                       cls_in_w, cls_in_b, cls_out_w, cls_out_b,
                                       logit_w, logit_b, (float*)d_out);
}